// Round 2
// baseline (482.137 us; speedup 1.0000x reference)
//
#include <hip/hip_runtime.h>
#include <hip/hip_bf16.h>
#include <stdint.h>

// ---------------------------------------------------------------------------
// MaskedAttention: out = colsoftmax(tril(Q K^T / sqrt(E))) @ V
// B=4, T=2048, E=H=1024.  Softmax over the QUERY axis (axis=1) per column j.
// All matmuls are NT bf16 MFMA GEMMs (K contiguous in both operands).
//
// Workspace budget: 80 MB (liveness overlays; previous 150 MB layout wrote
// past ws_size -> corrupted the harness's pristine input copies -> call 1
// passed, all later calls deterministically wrong).
//   [ 0,16) Xb      (dead after QKV)     -+-> S bf16 [0,32) at step 4
//   [16,22) Wq/k/vT (dead after QKV)     -+
//   [32,48) Qb      (dead after scores)  -+-> P bf16 [32,64) at step 5
//   [48,64) Kb      (dead after scores)  -+
//   [64,80) Vt [B,H,T] (alive to step 6, written directly by V-GEMM)
// ---------------------------------------------------------------------------

typedef short bf16x8 __attribute__((ext_vector_type(8)));
typedef float f32x4  __attribute__((ext_vector_type(4)));

__device__ __forceinline__ unsigned short f2bf(float f) {
    union { float f; unsigned u; } x; x.f = f;
    unsigned r = x.u + 0x7FFFu + ((x.u >> 16) & 1u);
    return (unsigned short)(r >> 16);
}
__device__ __forceinline__ float bf2f(unsigned short h) {
    union { unsigned u; float f; } x; x.u = ((unsigned)h) << 16;
    return x.f;
}

// 16B-per-lane async global->LDS copy. dst must be wave-uniform; HW adds lane*16.
__device__ __forceinline__ void async16(void* lds, const void* g) {
    __builtin_amdgcn_global_load_lds(
        (__attribute__((address_space(1))) void*)(void*)g,
        (__attribute__((address_space(3))) void*)lds,
        16, 0, 0);
}

// ---------------------------------------------------------------------------
__global__ __launch_bounds__(256) void cast_kernel(
    const float* __restrict__ in, unsigned short* __restrict__ out, size_t n)
{
    size_t i = ((size_t)blockIdx.x * 256 + threadIdx.x) * 4;
    if (i >= n) return;
    float4 v = *(const float4*)(in + i);
    union { unsigned short h[4]; unsigned long long u; } p;
    p.h[0] = f2bf(v.x); p.h[1] = f2bf(v.y); p.h[2] = f2bf(v.z); p.h[3] = f2bf(v.w);
    *(unsigned long long*)(out + i) = p.u;
}

// transpose + cast: W [R,C] fp32 -> Wt [C,R] bf16. 64x64 tile, 256 threads.
__global__ __launch_bounds__(256) void transpose_cast_kernel(
    const float* __restrict__ in, unsigned short* __restrict__ out, int R, int C)
{
    __shared__ unsigned short tile[64][65];
    int tx = threadIdx.x & 63, ty = threadIdx.x >> 6;
    int r0 = blockIdx.y * 64, c0 = blockIdx.x * 64;
#pragma unroll
    for (int i = 0; i < 16; ++i) {
        int r = ty + i * 4;
        tile[r][tx] = f2bf(in[(size_t)(r0 + r) * C + c0 + tx]);
    }
    __syncthreads();
#pragma unroll
    for (int i = 0; i < 16; ++i) {
        int c = ty + i * 4;
        out[(size_t)(c0 + c) * R + r0 + tx] = tile[tx][c];
    }
}

// ---------------------------------------------------------------------------
// NT bf16 GEMM: C[M,N] = A[M,K] * B[N,K]^T
// 128x128 tile, BK=32, 256 threads = 4 waves of 64x64, 16x16x32 bf16 MFMA.
// MODE 0: C bf16 row-major            (Q, K projections)
// MODE 1: C bf16 * scale, tm<tn skip  (scores, lower-triangle tiles only)
// MODE 2: C fp32, K limited to m0+128 (PV; P is causally zero-filled)
// MODE 3: C bf16 TRANSPOSED per batch (V projection -> Vt [B,H,T]), ldt = T
// ---------------------------------------------------------------------------
template <int MODE>
__global__ __launch_bounds__(256) void gemm_nt(
    const unsigned short* __restrict__ A, const unsigned short* __restrict__ B,
    void* __restrict__ Cout, int M, int N, int K,
    size_t sAb, size_t sBb, size_t sCb, float scale, int ldt)
{
    int tn = blockIdx.x, tm = blockIdx.y, bz = blockIdx.z;
    if (MODE == 1 && tm < tn) return;   // strictly-upper tile: never read later
    A += (size_t)bz * sAb;
    B += (size_t)bz * sBb;
    int m0 = tm * 128, n0 = tn * 128;
    int kmax = (MODE == 2) ? (m0 + 128) : K;

    __shared__ unsigned short sA[128 * 32];
    __shared__ unsigned short sB[128 * 32];

    unsigned t = threadIdx.x, lane = t & 63, wave = t >> 6;

    // staging: 512 chunks of 16B per tile; thread t does chunks t and t+256
    unsigned c0 = t, c1 = t + 256;
    const unsigned short* gA0 = A + (size_t)(m0 + (c0 >> 2)) * K + (c0 & 3) * 8;
    const unsigned short* gA1 = A + (size_t)(m0 + (c1 >> 2)) * K + (c1 & 3) * 8;
    const unsigned short* gB0 = B + (size_t)(n0 + (c0 >> 2)) * K + (c0 & 3) * 8;
    const unsigned short* gB1 = B + (size_t)(n0 + (c1 >> 2)) * K + (c1 & 3) * 8;
    char* lA0 = (char*)sA + wave * 1024;          // wave-uniform; HW adds lane*16
    char* lA1 = (char*)sA + 4096 + wave * 1024;
    char* lB0 = (char*)sB + wave * 1024;
    char* lB1 = (char*)sB + 4096 + wave * 1024;

    unsigned wm = (wave >> 1) * 64, wn = (wave & 1) * 64;
    unsigned lrow = lane & 15, lk = (lane >> 4) * 8;
    const short* sAs = (const short*)sA;
    const short* sBs = (const short*)sB;

    f32x4 acc[4][4] = {};

    for (int k0 = 0; k0 < kmax; k0 += 32) {
        __syncthreads();                 // prior iter's LDS reads complete
        async16(lA0, gA0); async16(lA1, gA1);
        async16(lB0, gB0); async16(lB1, gB1);
        gA0 += 32; gA1 += 32; gB0 += 32; gB1 += 32;
        __syncthreads();                 // vmcnt(0) drain before barrier

        bf16x8 a[4], b[4];
#pragma unroll
        for (int i = 0; i < 4; ++i) {
            a[i] = *(const bf16x8*)(sAs + (wm + i * 16 + lrow) * 32 + lk);
            b[i] = *(const bf16x8*)(sBs + (wn + i * 16 + lrow) * 32 + lk);
        }
#pragma unroll
        for (int i = 0; i < 4; ++i)
#pragma unroll
            for (int j = 0; j < 4; ++j)
                acc[i][j] = __builtin_amdgcn_mfma_f32_16x16x32_bf16(
                    a[i], b[j], acc[i][j], 0, 0, 0);
    }

    // epilogue: D col = lane&15, row = (lane>>4)*4 + reg
    unsigned col = lane & 15, rq = (lane >> 4) * 4;
    if (MODE == 0 || MODE == 1) {
        unsigned short* C = (unsigned short*)Cout + (size_t)bz * sCb;
#pragma unroll
        for (int i = 0; i < 4; ++i)
#pragma unroll
            for (int j = 0; j < 4; ++j)
#pragma unroll
                for (int r = 0; r < 4; ++r)
                    C[(size_t)(m0 + wm + i * 16 + rq + r) * N + n0 + wn + j * 16 + col] =
                        f2bf(acc[i][j][r] * scale);
    } else if (MODE == 2) {
        float* C = (float*)Cout + (size_t)bz * sCb;
#pragma unroll
        for (int i = 0; i < 4; ++i)
#pragma unroll
            for (int j = 0; j < 4; ++j)
#pragma unroll
                for (int r = 0; r < 4; ++r)
                    C[(size_t)(m0 + wm + i * 16 + rq + r) * N + n0 + wn + j * 16 + col] =
                        acc[i][j][r];
    } else { // MODE 3: transposed write, batch from row block; 4 bf16 packed (8B)
        unsigned short* C = (unsigned short*)Cout + (size_t)(m0 / ldt) * sCb;
        int tb = m0 % ldt;
#pragma unroll
        for (int i = 0; i < 4; ++i)
#pragma unroll
            for (int j = 0; j < 4; ++j) {
                union { unsigned short h[4]; unsigned long long u; } p;
#pragma unroll
                for (int r = 0; r < 4; ++r) p.h[r] = f2bf(acc[i][j][r]);
                int h = n0 + wn + j * 16 + col;
                int t0 = tb + wm + i * 16 + rq;
                *(unsigned long long*)(C + (size_t)h * ldt + t0) = p.u;
            }
    }
}

// ---------------------------------------------------------------------------
// column softmax (over query axis i, per column j), causal: entries i<j = 0.
// Block = 32 columns x 8 i-groups. Online (m,l) pass 1, write pass 2.
// Writes FULL P (zeros above diagonal) so PV GEMM needs no masking.
// ---------------------------------------------------------------------------
__global__ __launch_bounds__(256) void col_softmax(
    const unsigned short* __restrict__ S, unsigned short* __restrict__ P, int T)
{
    int b = blockIdx.y;
    const unsigned short* Sb = S + (size_t)b * T * T;
    unsigned short* Pb = P + (size_t)b * T * T;
    int jl = threadIdx.x & 31;
    int ig = threadIdx.x >> 5;          // 0..7
    int j = blockIdx.x * 32 + jl;

    float m = -1e30f, l = 0.f;
    for (int i = ig; i < T; i += 8) {
        if (i >= j) {
            float s = bf2f(Sb[(size_t)i * T + j]);
            if (s > m) { l = l * __expf(m - s) + 1.f; m = s; }
            else       { l += __expf(s - m); }
        }
    }
    __shared__ float sm[8][32], sl[8][32];
    __shared__ float fm[32], fl[32];
    sm[ig][jl] = m; sl[ig][jl] = l;
    __syncthreads();
    if (ig == 0) {
        float M = -1e30f;
#pragma unroll
        for (int g = 0; g < 8; ++g) M = fmaxf(M, sm[g][jl]);
        float L = 0.f;
#pragma unroll
        for (int g = 0; g < 8; ++g) L += sl[g][jl] * __expf(sm[g][jl] - M);
        fm[jl] = M; fl[jl] = 1.0f / L;
    }
    __syncthreads();
    float M = fm[jl], Linv = fl[jl];
    for (int i = ig; i < T; i += 8) {
        float v = 0.f;
        if (i >= j) v = __expf(bf2f(Sb[(size_t)i * T + j]) - M) * Linv;
        Pb[(size_t)i * T + j] = f2bf(v);
    }
}

// ---------------------------------------------------------------------------
extern "C" void kernel_launch(void* const* d_in, const int* in_sizes, int n_in,
                              void* d_out, int out_size, void* d_ws, size_t ws_size,
                              hipStream_t stream)
{
    const int B = 4, T = 2048, E = 1024, H = 1024;
    const int M = B * T;                       // 8192
    const float* X  = (const float*)d_in[0];
    const float* Wq = (const float*)d_in[1];
    const float* Wk = (const float*)d_in[2];
    const float* Wv = (const float*)d_in[3];
    float* out = (float*)d_out;
    char* ws = (char*)d_ws;
    const size_t MB = 1024 * 1024;

    unsigned short* Xb  = (unsigned short*)(ws + 0);        // [ 0,16) MB
    unsigned short* WqT = (unsigned short*)(ws + 16 * MB);  // [16,18)
    unsigned short* WkT = (unsigned short*)(ws + 18 * MB);  // [18,20)
    unsigned short* WvT = (unsigned short*)(ws + 20 * MB);  // [20,22)
    unsigned short* Qb  = (unsigned short*)(ws + 32 * MB);  // [32,48)
    unsigned short* Kb  = (unsigned short*)(ws + 48 * MB);  // [48,64)
    unsigned short* Vt  = (unsigned short*)(ws + 64 * MB);  // [64,80)  [B,H,T]
    unsigned short* S   = (unsigned short*)(ws + 0);        // [ 0,32)  overlays Xb/W (dead)
    unsigned short* P   = (unsigned short*)(ws + 32 * MB);  // [32,64)  overlays Qb/Kb (dead)

    // 1. casts / weight transposes
    cast_kernel<<<dim3((M * E) / 1024), 256, 0, stream>>>(X, Xb, (size_t)M * E);
    transpose_cast_kernel<<<dim3(H / 64, E / 64), 256, 0, stream>>>(Wq, WqT, E, H);
    transpose_cast_kernel<<<dim3(H / 64, E / 64), 256, 0, stream>>>(Wk, WkT, E, H);
    transpose_cast_kernel<<<dim3(H / 64, E / 64), 256, 0, stream>>>(Wv, WvT, E, H);

    // 2. projections: Q,K row-major bf16; V written directly transposed [B,H,T]
    gemm_nt<0><<<dim3(H / 128, M / 128, 1), 256, 0, stream>>>(
        Xb, WqT, Qb, M, H, E, 0, 0, 0, 1.f, 0);
    gemm_nt<0><<<dim3(H / 128, M / 128, 1), 256, 0, stream>>>(
        Xb, WkT, Kb, M, H, E, 0, 0, 0, 1.f, 0);
    gemm_nt<3><<<dim3(H / 128, M / 128, 1), 256, 0, stream>>>(
        Xb, WvT, Vt, M, H, E, 0, 0, (size_t)H * T, 1.f, T);

    // 3. scores: S = Q K^T / 32 (bf16), lower-triangle tiles only
    gemm_nt<1><<<dim3(T / 128, T / 128, B), 256, 0, stream>>>(
        Qb, Kb, S, T, T, H, (size_t)T * H, (size_t)T * H, (size_t)T * T, 0.03125f, 0);

    // 4. column softmax over i (query axis), P bf16 zero-filled above diagonal
    col_softmax<<<dim3(T / 32, B), 256, 0, stream>>>(S, P, T);

    // 5. out = P V  (NT with V^T), causal K-limit
    gemm_nt<2><<<dim3(H / 128, T / 128, B), 256, 0, stream>>>(
        P, Vt, out, T, H, T, (size_t)T * T, (size_t)H * T, (size_t)T * H, 1.f, 0);
}

// Round 3
// 349.258 us; speedup vs baseline: 1.3805x; 1.3805x over previous
//
#include <hip/hip_runtime.h>
#include <hip/hip_bf16.h>
#include <stdint.h>

// ---------------------------------------------------------------------------
// MaskedAttention: out = colsoftmax(tril(Q K^T / sqrt(E))) @ V
// B=4, T=2048, E=H=1024.  Softmax over the QUERY axis (axis=1) per column j.
// All matmuls are NT bf16 MFMA GEMMs (K contiguous in both operands).
//
// R3 change: scores GEMM writes S TRANSPOSED (St[j][i]) so the column softmax
// becomes row-contiguous (R2 profile: col_softmax was 178 us at 4.7% HBM,
// 4.8% VALU -- latency-bound on 2-byte stride-4KB column loads).
//
// Workspace 80 MB, liveness overlays:
//   [ 0,16) Xb      (dead after QKV)     -+-> St bf16 [0,32) at scores step
//   [16,22) Wq/k/vT (dead after QKV)     -+
//   [32,48) Qb      (dead after scores)  -+-> P bf16 [32,64) at softmax step
//   [48,64) Kb      (dead after scores)  -+
//   [64,80) Vt [B,H,T] (alive to PV, written directly by V-GEMM epilogue)
// ---------------------------------------------------------------------------

typedef short bf16x8 __attribute__((ext_vector_type(8)));
typedef float f32x4  __attribute__((ext_vector_type(4)));

__device__ __forceinline__ unsigned short f2bf(float f) {
    union { float f; unsigned u; } x; x.f = f;
    unsigned r = x.u + 0x7FFFu + ((x.u >> 16) & 1u);
    return (unsigned short)(r >> 16);
}
__device__ __forceinline__ float bf2f(unsigned short h) {
    union { unsigned u; float f; } x; x.u = ((unsigned)h) << 16;
    return x.f;
}

// 16B-per-lane async global->LDS copy. dst must be wave-uniform; HW adds lane*16.
__device__ __forceinline__ void async16(void* lds, const void* g) {
    __builtin_amdgcn_global_load_lds(
        (__attribute__((address_space(1))) void*)(void*)g,
        (__attribute__((address_space(3))) void*)lds,
        16, 0, 0);
}

// ---------------------------------------------------------------------------
__global__ __launch_bounds__(256) void cast_kernel(
    const float* __restrict__ in, unsigned short* __restrict__ out, size_t n)
{
    size_t i = ((size_t)blockIdx.x * 256 + threadIdx.x) * 4;
    if (i >= n) return;
    float4 v = *(const float4*)(in + i);
    union { unsigned short h[4]; unsigned long long u; } p;
    p.h[0] = f2bf(v.x); p.h[1] = f2bf(v.y); p.h[2] = f2bf(v.z); p.h[3] = f2bf(v.w);
    *(unsigned long long*)(out + i) = p.u;
}

// transpose + cast: W [R,C] fp32 -> Wt [C,R] bf16. 64x64 tile, 256 threads.
__global__ __launch_bounds__(256) void transpose_cast_kernel(
    const float* __restrict__ in, unsigned short* __restrict__ out, int R, int C)
{
    __shared__ unsigned short tile[64][65];
    int tx = threadIdx.x & 63, ty = threadIdx.x >> 6;
    int r0 = blockIdx.y * 64, c0 = blockIdx.x * 64;
#pragma unroll
    for (int i = 0; i < 16; ++i) {
        int r = ty + i * 4;
        tile[r][tx] = f2bf(in[(size_t)(r0 + r) * C + c0 + tx]);
    }
    __syncthreads();
#pragma unroll
    for (int i = 0; i < 16; ++i) {
        int c = ty + i * 4;
        out[(size_t)(c0 + c) * R + r0 + tx] = tile[tx][c];
    }
}

// ---------------------------------------------------------------------------
// NT bf16 GEMM: C[M,N] = A[M,K] * B[N,K]^T
// 128x128 tile, BK=32, 256 threads = 4 waves of 64x64, 16x16x32 bf16 MFMA.
// MODE 0: C bf16 row-major                       (Q, K projections)
// MODE 1: C bf16 TRANSPOSED * scale, tm<tn skip  (scores -> St[j][i]), ldt=T
// MODE 2: C fp32, K limited to m0+128            (PV; P causally zero-filled)
// MODE 3: C bf16 TRANSPOSED, batch from rows     (V -> Vt [B,H,T]), ldt=T
// ---------------------------------------------------------------------------
template <int MODE>
__global__ __launch_bounds__(256) void gemm_nt(
    const unsigned short* __restrict__ A, const unsigned short* __restrict__ B,
    void* __restrict__ Cout, int M, int N, int K,
    size_t sAb, size_t sBb, size_t sCb, float scale, int ldt)
{
    int tn = blockIdx.x, tm = blockIdx.y, bz = blockIdx.z;
    if (MODE == 1 && tm < tn) return;   // strictly-upper tile: never read later
    A += (size_t)bz * sAb;
    B += (size_t)bz * sBb;
    int m0 = tm * 128, n0 = tn * 128;
    int kmax = (MODE == 2) ? (m0 + 128) : K;

    __shared__ unsigned short sA[128 * 32];
    __shared__ unsigned short sB[128 * 32];

    unsigned t = threadIdx.x, lane = t & 63, wave = t >> 6;

    // staging: 512 chunks of 16B per tile; thread t does chunks t and t+256
    unsigned c0 = t, c1 = t + 256;
    const unsigned short* gA0 = A + (size_t)(m0 + (c0 >> 2)) * K + (c0 & 3) * 8;
    const unsigned short* gA1 = A + (size_t)(m0 + (c1 >> 2)) * K + (c1 & 3) * 8;
    const unsigned short* gB0 = B + (size_t)(n0 + (c0 >> 2)) * K + (c0 & 3) * 8;
    const unsigned short* gB1 = B + (size_t)(n0 + (c1 >> 2)) * K + (c1 & 3) * 8;
    char* lA0 = (char*)sA + wave * 1024;          // wave-uniform; HW adds lane*16
    char* lA1 = (char*)sA + 4096 + wave * 1024;
    char* lB0 = (char*)sB + wave * 1024;
    char* lB1 = (char*)sB + 4096 + wave * 1024;

    unsigned wm = (wave >> 1) * 64, wn = (wave & 1) * 64;
    unsigned lrow = lane & 15, lk = (lane >> 4) * 8;
    const short* sAs = (const short*)sA;
    const short* sBs = (const short*)sB;

    f32x4 acc[4][4] = {};

    for (int k0 = 0; k0 < kmax; k0 += 32) {
        __syncthreads();                 // prior iter's LDS reads complete
        async16(lA0, gA0); async16(lA1, gA1);
        async16(lB0, gB0); async16(lB1, gB1);
        gA0 += 32; gA1 += 32; gB0 += 32; gB1 += 32;
        __syncthreads();                 // vmcnt(0) drain before barrier

        bf16x8 a[4], b[4];
#pragma unroll
        for (int i = 0; i < 4; ++i) {
            a[i] = *(const bf16x8*)(sAs + (wm + i * 16 + lrow) * 32 + lk);
            b[i] = *(const bf16x8*)(sBs + (wn + i * 16 + lrow) * 32 + lk);
        }
#pragma unroll
        for (int i = 0; i < 4; ++i)
#pragma unroll
            for (int j = 0; j < 4; ++j)
                acc[i][j] = __builtin_amdgcn_mfma_f32_16x16x32_bf16(
                    a[i], b[j], acc[i][j], 0, 0, 0);
    }

    // epilogue: D col = lane&15, row = (lane>>4)*4 + reg
    unsigned col = lane & 15, rq = (lane >> 4) * 4;
    if (MODE == 0) {
        unsigned short* C = (unsigned short*)Cout + (size_t)bz * sCb;
#pragma unroll
        for (int i = 0; i < 4; ++i)
#pragma unroll
            for (int j = 0; j < 4; ++j)
#pragma unroll
                for (int r = 0; r < 4; ++r)
                    C[(size_t)(m0 + wm + i * 16 + rq + r) * N + n0 + wn + j * 16 + col] =
                        f2bf(acc[i][j][r]);
    } else if (MODE == 1) {   // transposed + scale: St[j][i], 4 bf16 packed
        unsigned short* C = (unsigned short*)Cout + (size_t)bz * sCb;
#pragma unroll
        for (int i = 0; i < 4; ++i)
#pragma unroll
            for (int j = 0; j < 4; ++j) {
                union { unsigned short h[4]; unsigned long long u; } p;
#pragma unroll
                for (int r = 0; r < 4; ++r) p.h[r] = f2bf(acc[i][j][r] * scale);
                int jg = n0 + wn + j * 16 + col;
                int ig = m0 + wm + i * 16 + rq;
                *(unsigned long long*)(C + (size_t)jg * ldt + ig) = p.u;
            }
    } else if (MODE == 2) {
        float* C = (float*)Cout + (size_t)bz * sCb;
#pragma unroll
        for (int i = 0; i < 4; ++i)
#pragma unroll
            for (int j = 0; j < 4; ++j)
#pragma unroll
                for (int r = 0; r < 4; ++r)
                    C[(size_t)(m0 + wm + i * 16 + rq + r) * N + n0 + wn + j * 16 + col] =
                        acc[i][j][r];
    } else { // MODE 3: transposed write, batch from row block; 4 bf16 packed
        unsigned short* C = (unsigned short*)Cout + (size_t)(m0 / ldt) * sCb;
        int tb = m0 % ldt;
#pragma unroll
        for (int i = 0; i < 4; ++i)
#pragma unroll
            for (int j = 0; j < 4; ++j) {
                union { unsigned short h[4]; unsigned long long u; } p;
#pragma unroll
                for (int r = 0; r < 4; ++r) p.h[r] = f2bf(acc[i][j][r]);
                int h = n0 + wn + j * 16 + col;
                int t0 = tb + wm + i * 16 + rq;
                *(unsigned long long*)(C + (size_t)h * ldt + t0) = p.u;
            }
    }
}

// ---------------------------------------------------------------------------
// Softmax over query axis i (per column j), on TRANSPOSED scores St[j][i].
// Rows of St are i-contiguous -> fully coalesced.  Causal: p=0 for i<j.
// Block = 32 columns (j0..j0+31), 256 threads (4 waves).
// Phase 1: wave w owns j = j0+8w..+7; 64 lanes x bf16x8 = 512 i per chunk,
//          lane-local online (m,l), shfl_xor butterfly merge.  Chunks start
//          at j>>9 (causal skip).
// Phase 2: stream 64-i chunks: compute p, transpose via LDS (f32, stride 33,
//          <=2-way banks), write P[i][j0..j0+31] as 64B contiguous segments.
//          Chunks start at (j0 & ~127)/64 so the PV GEMM's diagonal 128-tiles
//          see explicit zeros above the diagonal.
// ---------------------------------------------------------------------------
__global__ __launch_bounds__(256) void col_softmax_t(
    const unsigned short* __restrict__ St, unsigned short* __restrict__ P, int T)
{
    const int b = blockIdx.y;
    const int j0 = blockIdx.x * 32;
    const unsigned short* Sb = St + (size_t)b * T * T;
    unsigned short* Pb = P + (size_t)b * T * T;
    const int t = threadIdx.x, lane = t & 63, wave = t >> 6;

    __shared__ float fm[32], fl[32];
    __shared__ float tile[64 * 33];

    // ---- phase 1: per-column max & sum ----
    for (int jj = 0; jj < 8; ++jj) {
        const int jl = wave * 8 + jj, j = j0 + jl;
        const unsigned short* row = Sb + (size_t)j * T;
        float m = -1e30f, l = 0.f;
        for (int it = j >> 9; it < (T >> 9); ++it) {
            const int i0 = it * 512 + lane * 8;
            bf16x8 v = *(const bf16x8*)(row + i0);
            float s[8];
#pragma unroll
            for (int e = 0; e < 8; ++e)
                s[e] = (i0 + e >= j) ? bf2f((unsigned short)v[e]) : -1e30f;
            float m8 = s[0];
#pragma unroll
            for (int e = 1; e < 8; ++e) m8 = fmaxf(m8, s[e]);
            const float mn = fmaxf(m, m8);
            float a = 0.f;
#pragma unroll
            for (int e = 0; e < 8; ++e) a += __expf(s[e] - mn);
            l = l * __expf(m - mn) + a;   // stale-chunk garbage flushes to 0
            m = mn;                       // once a real max arrives
        }
#pragma unroll
        for (int d = 1; d < 64; d <<= 1) {
            const float mo = __shfl_xor(m, d);
            const float lo = __shfl_xor(l, d);
            const float mn = fmaxf(m, mo);
            l = l * __expf(m - mn) + lo * __expf(mo - mn);
            m = mn;
        }
        if (lane == 0) { fm[jl] = m; fl[jl] = 1.0f / l; }
    }
    __syncthreads();

    // ---- phase 2: probabilities + LDS transpose + coalesced P write ----
    const int jl = t >> 3;               // 0..31
    const int j = j0 + jl;
    const int is = (t & 7) * 8;          // 0..56
    const float M = fm[jl], Li = fl[jl];
    const int il = t >> 3, jo = (t & 7) * 4;

    for (int ic = (j0 >> 7) << 1; ic < (T >> 6); ++ic) {
        bf16x8 v = *(const bf16x8*)(Sb + (size_t)j * T + ic * 64 + is);
#pragma unroll
        for (int k = 0; k < 8; ++k) {
            const int i = ic * 64 + is + k;
            const float s = bf2f((unsigned short)v[k]);
            tile[(is + k) * 33 + jl] = (i >= j) ? __expf(s - M) * Li : 0.f;
        }
        __syncthreads();
#pragma unroll
        for (int r = 0; r < 2; ++r) {
            const int ir = il + r * 32;
            union { unsigned short h[4]; unsigned long long u; } pk;
#pragma unroll
            for (int e = 0; e < 4; ++e) pk.h[e] = f2bf(tile[ir * 33 + jo + e]);
            *(unsigned long long*)(Pb + (size_t)(ic * 64 + ir) * T + j0 + jo) = pk.u;
        }
        __syncthreads();
    }
}

// ---------------------------------------------------------------------------
extern "C" void kernel_launch(void* const* d_in, const int* in_sizes, int n_in,
                              void* d_out, int out_size, void* d_ws, size_t ws_size,
                              hipStream_t stream)
{
    const int B = 4, T = 2048, E = 1024, H = 1024;
    const int M = B * T;                       // 8192
    const float* X  = (const float*)d_in[0];
    const float* Wq = (const float*)d_in[1];
    const float* Wk = (const float*)d_in[2];
    const float* Wv = (const float*)d_in[3];
    float* out = (float*)d_out;
    char* ws = (char*)d_ws;
    const size_t MB = 1024 * 1024;

    unsigned short* Xb  = (unsigned short*)(ws + 0);        // [ 0,16) MB
    unsigned short* WqT = (unsigned short*)(ws + 16 * MB);  // [16,18)
    unsigned short* WkT = (unsigned short*)(ws + 18 * MB);  // [18,20)
    unsigned short* WvT = (unsigned short*)(ws + 20 * MB);  // [20,22)
    unsigned short* Qb  = (unsigned short*)(ws + 32 * MB);  // [32,48)
    unsigned short* Kb  = (unsigned short*)(ws + 48 * MB);  // [48,64)
    unsigned short* Vt  = (unsigned short*)(ws + 64 * MB);  // [64,80)  [B,H,T]
    unsigned short* St  = (unsigned short*)(ws + 0);        // [ 0,32)  overlays Xb/W (dead)
    unsigned short* P   = (unsigned short*)(ws + 32 * MB);  // [32,64)  overlays Qb/Kb (dead)

    // 1. casts / weight transposes
    cast_kernel<<<dim3((M * E) / 1024), 256, 0, stream>>>(X, Xb, (size_t)M * E);
    transpose_cast_kernel<<<dim3(H / 64, E / 64), 256, 0, stream>>>(Wq, WqT, E, H);
    transpose_cast_kernel<<<dim3(H / 64, E / 64), 256, 0, stream>>>(Wk, WkT, E, H);
    transpose_cast_kernel<<<dim3(H / 64, E / 64), 256, 0, stream>>>(Wv, WvT, E, H);

    // 2. projections: Q,K row-major bf16; V written directly transposed [B,H,T]
    gemm_nt<0><<<dim3(H / 128, M / 128, 1), 256, 0, stream>>>(
        Xb, WqT, Qb, M, H, E, 0, 0, 0, 1.f, 0);
    gemm_nt<0><<<dim3(H / 128, M / 128, 1), 256, 0, stream>>>(
        Xb, WkT, Kb, M, H, E, 0, 0, 0, 1.f, 0);
    gemm_nt<3><<<dim3(H / 128, M / 128, 1), 256, 0, stream>>>(
        Xb, WvT, Vt, M, H, E, 0, 0, (size_t)H * T, 1.f, T);

    // 3. scores, written TRANSPOSED: St[j][i] = (Q K^T)[i][j] / 32
    gemm_nt<1><<<dim3(T / 128, T / 128, B), 256, 0, stream>>>(
        Qb, Kb, St, T, T, H, (size_t)T * H, (size_t)T * H, (size_t)T * T, 0.03125f, T);

    // 4. softmax over i per column j (row-contiguous on St), P[i][j] bf16
    col_softmax_t<<<dim3(T / 32, B), 256, 0, stream>>>(St, P, T);

    // 5. out = P V  (NT with V^T), causal K-limit
    gemm_nt<2><<<dim3(H / 128, T / 128, B), 256, 0, stream>>>(
        P, Vt, out, T, H, T, (size_t)T * T, (size_t)H * T, (size_t)T * H, 1.f, 0);
}

// Round 5
// 290.302 us; speedup vs baseline: 1.6608x; 1.2031x over previous
//
#include <hip/hip_runtime.h>
#include <hip/hip_bf16.h>
#include <stdint.h>

// ---------------------------------------------------------------------------
// MaskedAttention: out = colsoftmax(tril(Q K^T / sqrt(E))) @ V
// B=4, T=2048, E=H=1024.  Softmax over the QUERY axis (axis=1) per column j.
//
// R4/R5 changes (R3 profile: all 5 GEMMs ~71 us each, MfmaUtil 9.7%, VALU 17%,
// HBM 14%, occupancy 10.7% -> latency-bound, grid gives only 2 blocks/CU):
//  * QKV fused into ONE GEMM vs concat weights [3072,1024] -> 1536 blocks
//    (6 blocks/CU), Xb read once, one dispatch.
//  * BK=64 as two consecutive BK=32 sub-tiles (same proven LDS layout per
//    half): 8 loads in flight/thread, 32 MFMA per barrier drain (2x).
//  (R4 failed to compile: trailing backslash in a comment spliced away the
//   WkT declaration. No trailing backslashes in comments.)
//
// Workspace 80 MB, liveness overlays:
//   [ 0,16) Xb      (dead after QKV)      -> St bf16 [0,32) at scores step
//   [16,22) WqT|WkT|WvT contiguous [3072,1024] (dead after QKV)
//   [32,48) Qb      (dead after scores)   -> P bf16 [32,64) at softmax step
//   [48,64) Kb      (dead after scores)
//   [64,80) Vt [B,H,T] (alive to PV, written by fused-GEMM V epilogue)
// ---------------------------------------------------------------------------

typedef short bf16x8 __attribute__((ext_vector_type(8)));
typedef float f32x4  __attribute__((ext_vector_type(4)));

__device__ __forceinline__ unsigned short f2bf(float f) {
    union { float f; unsigned u; } x; x.f = f;
    unsigned r = x.u + 0x7FFFu + ((x.u >> 16) & 1u);
    return (unsigned short)(r >> 16);
}
__device__ __forceinline__ float bf2f(unsigned short h) {
    union { unsigned u; float f; } x; x.u = ((unsigned)h) << 16;
    return x.f;
}

// 16B-per-lane async global->LDS copy. dst must be wave-uniform; HW adds lane*16.
__device__ __forceinline__ void async16(void* lds, const void* g) {
    __builtin_amdgcn_global_load_lds(
        (__attribute__((address_space(1))) void*)(void*)g,
        (__attribute__((address_space(3))) void*)lds,
        16, 0, 0);
}

// ---------------------------------------------------------------------------
__global__ __launch_bounds__(256) void cast_kernel(
    const float* __restrict__ in, unsigned short* __restrict__ out, size_t n)
{
    size_t i = ((size_t)blockIdx.x * 256 + threadIdx.x) * 4;
    if (i >= n) return;
    float4 v = *(const float4*)(in + i);
    union { unsigned short h[4]; unsigned long long u; } p;
    p.h[0] = f2bf(v.x); p.h[1] = f2bf(v.y); p.h[2] = f2bf(v.z); p.h[3] = f2bf(v.w);
    *(unsigned long long*)(out + i) = p.u;
}

// transpose + cast: W [R,C] fp32 -> Wt [C,R] bf16. 64x64 tile, 256 threads.
__global__ __launch_bounds__(256) void transpose_cast_kernel(
    const float* __restrict__ in, unsigned short* __restrict__ out, int R, int C)
{
    __shared__ unsigned short tile[64][65];
    int tx = threadIdx.x & 63, ty = threadIdx.x >> 6;
    int r0 = blockIdx.y * 64, c0 = blockIdx.x * 64;
#pragma unroll
    for (int i = 0; i < 16; ++i) {
        int r = ty + i * 4;
        tile[r][tx] = f2bf(in[(size_t)(r0 + r) * C + c0 + tx]);
    }
    __syncthreads();
#pragma unroll
    for (int i = 0; i < 16; ++i) {
        int c = ty + i * 4;
        out[(size_t)(c0 + c) * R + r0 + tx] = tile[tx][c];
    }
}

// ---------------------------------------------------------------------------
// NT bf16 GEMM: C[M,N] = A[M,K] * B[N,K]^T
// 128x128 tile, BK=64 (two BK=32 halves), 256 threads = 4 waves of 64x64,
// 16x16x32 bf16 MFMA, width-16 global_load_lds staging (8/thread/iter).
// MODE 1: C bf16 TRANSPOSED * scale, tm<tn skip  (scores -> St[j][i]), ldt=T
// MODE 2: C fp32, K limited to m0+128            (PV; P causally zero-filled)
// MODE 4: fused QKV epilogue: n0<1024 -> Cout (Q rowmajor), <2048 -> C2 (K
//         rowmajor), else C3 (V transposed [B,H,T], batch from m0), ldt=T
// ---------------------------------------------------------------------------
template <int MODE>
__global__ __launch_bounds__(256) void gemm_nt(
    const unsigned short* __restrict__ A, const unsigned short* __restrict__ B,
    void* __restrict__ Cout, unsigned short* __restrict__ C2,
    unsigned short* __restrict__ C3, int M, int N, int K,
    size_t sAb, size_t sBb, size_t sCb, float scale, int ldt)
{
    int tn = blockIdx.x, tm = blockIdx.y, bz = blockIdx.z;
    if (MODE == 1 && tm < tn) return;   // strictly-upper tile: never read later
    A += (size_t)bz * sAb;
    B += (size_t)bz * sBb;
    int m0 = tm * 128, n0 = tn * 128;
    int kmax = (MODE == 2) ? (m0 + 128) : K;

    __shared__ unsigned short sA[128 * 64];   // two 128x32 halves, consecutive
    __shared__ unsigned short sB[128 * 64];

    unsigned t = threadIdx.x, lane = t & 63, wave = t >> 6;

    // staging: 1024 16B-chunks per tile; chunk ca: half = ca>>9,
    // row = (ca&511)>>2, colE = half*32 + (ca&3)*8; LDS byte offset = ca*16.
    const unsigned short* gA[4]; const unsigned short* gB[4];
    char* lA[4]; char* lB[4];
#pragma unroll
    for (int q = 0; q < 4; ++q) {
        unsigned ca = t + 256u * q;
        unsigned row = (ca & 511) >> 2;
        unsigned col = (ca >> 9) * 32 + (ca & 3) * 8;
        gA[q] = A + (size_t)(m0 + row) * K + col;
        gB[q] = B + (size_t)(n0 + row) * K + col;
        lA[q] = (char*)sA + (size_t)(t - lane + 256u * q) * 16;
        lB[q] = (char*)sB + (size_t)(t - lane + 256u * q) * 16;
    }

    unsigned wm = (wave >> 1) * 64, wn = (wave & 1) * 64;
    unsigned lrow = lane & 15, lk = (lane >> 4) * 8;
    const short* sAs = (const short*)sA;
    const short* sBs = (const short*)sB;

    f32x4 acc[4][4] = {};

    for (int k0 = 0; k0 < kmax; k0 += 64) {
        __syncthreads();                 // prior iter's LDS reads complete
#pragma unroll
        for (int q = 0; q < 4; ++q) {
            async16(lA[q], gA[q]); async16(lB[q], gB[q]);
            gA[q] += 64; gB[q] += 64;
        }
        __syncthreads();                 // vmcnt(0) drain before barrier

#pragma unroll
        for (int kk = 0; kk < 2; ++kk) {
            bf16x8 a[4], b[4];
#pragma unroll
            for (int i = 0; i < 4; ++i) {
                a[i] = *(const bf16x8*)(sAs + kk * 4096 + (wm + i * 16 + lrow) * 32 + lk);
                b[i] = *(const bf16x8*)(sBs + kk * 4096 + (wn + i * 16 + lrow) * 32 + lk);
            }
#pragma unroll
            for (int i = 0; i < 4; ++i)
#pragma unroll
                for (int j = 0; j < 4; ++j)
                    acc[i][j] = __builtin_amdgcn_mfma_f32_16x16x32_bf16(
                        a[i], b[j], acc[i][j], 0, 0, 0);
        }
    }

    // epilogue: D col = lane&15, row = (lane>>4)*4 + reg
    unsigned col = lane & 15, rq = (lane >> 4) * 4;
    if (MODE == 1) {          // transposed + scale: St[j][i], 4 bf16 packed
        unsigned short* C = (unsigned short*)Cout + (size_t)bz * sCb;
#pragma unroll
        for (int i = 0; i < 4; ++i)
#pragma unroll
            for (int j = 0; j < 4; ++j) {
                union { unsigned short h[4]; unsigned long long u; } p;
#pragma unroll
                for (int r = 0; r < 4; ++r) p.h[r] = f2bf(acc[i][j][r] * scale);
                int jg = n0 + wn + j * 16 + col;
                int ig = m0 + wm + i * 16 + rq;
                *(unsigned long long*)(C + (size_t)jg * ldt + ig) = p.u;
            }
    } else if (MODE == 2) {
        float* C = (float*)Cout + (size_t)bz * sCb;
#pragma unroll
        for (int i = 0; i < 4; ++i)
#pragma unroll
            for (int j = 0; j < 4; ++j)
#pragma unroll
                for (int r = 0; r < 4; ++r)
                    C[(size_t)(m0 + wm + i * 16 + rq + r) * N + n0 + wn + j * 16 + col] =
                        acc[i][j][r];
    } else {                  // MODE 4: fused QKV
        if (n0 < 2048) {      // Q or K, row-major [8192,1024]
            unsigned short* C = (n0 < 1024) ? (unsigned short*)Cout : C2;
            int nb = n0 & 1023;
#pragma unroll
            for (int i = 0; i < 4; ++i)
#pragma unroll
                for (int j = 0; j < 4; ++j)
#pragma unroll
                    for (int r = 0; r < 4; ++r)
                        C[(size_t)(m0 + wm + i * 16 + rq + r) * 1024 + nb + wn + j * 16 + col] =
                            f2bf(acc[i][j][r]);
        } else {              // V transposed into Vt [B,H,T]
            int batch = m0 >> 11, tb = m0 & 2047;
            unsigned short* C = C3 + (size_t)batch * 1024 * 2048;
#pragma unroll
            for (int i = 0; i < 4; ++i)
#pragma unroll
                for (int j = 0; j < 4; ++j) {
                    union { unsigned short h[4]; unsigned long long u; } p;
#pragma unroll
                    for (int r = 0; r < 4; ++r) p.h[r] = f2bf(acc[i][j][r]);
                    int h = (n0 - 2048) + wn + j * 16 + col;
                    int t0 = tb + wm + i * 16 + rq;
                    *(unsigned long long*)(C + (size_t)h * ldt + t0) = p.u;
                }
        }
    }
}

// ---------------------------------------------------------------------------
// Softmax over query axis i (per column j), on TRANSPOSED scores St[j][i].
// Block = 32 columns, 256 threads. Phase 1: per-column online (m,l) with
// bf16x8 coalesced loads + shfl butterfly. Phase 2: p + LDS transpose +
// coalesced P[i][j] writes (zeros above diagonal for PV's diagonal tiles).
// ---------------------------------------------------------------------------
__global__ __launch_bounds__(256) void col_softmax_t(
    const unsigned short* __restrict__ St, unsigned short* __restrict__ P, int T)
{
    const int b = blockIdx.y;
    const int j0 = blockIdx.x * 32;
    const unsigned short* Sb = St + (size_t)b * T * T;
    unsigned short* Pb = P + (size_t)b * T * T;
    const int t = threadIdx.x, lane = t & 63, wave = t >> 6;

    __shared__ float fm[32], fl[32];
    __shared__ float tile[64 * 33];

    // ---- phase 1: per-column max & sum ----
    for (int jj = 0; jj < 8; ++jj) {
        const int jl = wave * 8 + jj, j = j0 + jl;
        const unsigned short* row = Sb + (size_t)j * T;
        float m = -1e30f, l = 0.f;
        for (int it = j >> 9; it < (T >> 9); ++it) {
            const int i0 = it * 512 + lane * 8;
            bf16x8 v = *(const bf16x8*)(row + i0);
            float s[8];
#pragma unroll
            for (int e = 0; e < 8; ++e)
                s[e] = (i0 + e >= j) ? bf2f((unsigned short)v[e]) : -1e30f;
            float m8 = s[0];
#pragma unroll
            for (int e = 1; e < 8; ++e) m8 = fmaxf(m8, s[e]);
            const float mn = fmaxf(m, m8);
            float a = 0.f;
#pragma unroll
            for (int e = 0; e < 8; ++e) a += __expf(s[e] - mn);
            l = l * __expf(m - mn) + a;
            m = mn;
        }
#pragma unroll
        for (int d = 1; d < 64; d <<= 1) {
            const float mo = __shfl_xor(m, d);
            const float lo = __shfl_xor(l, d);
            const float mn = fmaxf(m, mo);
            l = l * __expf(m - mn) + lo * __expf(mo - mn);
            m = mn;
        }
        if (lane == 0) { fm[jl] = m; fl[jl] = 1.0f / l; }
    }
    __syncthreads();

    // ---- phase 2: probabilities + LDS transpose + coalesced P write ----
    const int jl = t >> 3;               // 0..31
    const int j = j0 + jl;
    const int is = (t & 7) * 8;          // 0..56
    const float M = fm[jl], Li = fl[jl];
    const int il = t >> 3, jo = (t & 7) * 4;

    for (int ic = (j0 >> 7) << 1; ic < (T >> 6); ++ic) {
        bf16x8 v = *(const bf16x8*)(Sb + (size_t)j * T + ic * 64 + is);
#pragma unroll
        for (int k = 0; k < 8; ++k) {
            const int i = ic * 64 + is + k;
            const float s = bf2f((unsigned short)v[k]);
            tile[(is + k) * 33 + jl] = (i >= j) ? __expf(s - M) * Li : 0.f;
        }
        __syncthreads();
#pragma unroll
        for (int r = 0; r < 2; ++r) {
            const int ir = il + r * 32;
            union { unsigned short h[4]; unsigned long long u; } pk;
#pragma unroll
            for (int e = 0; e < 4; ++e) pk.h[e] = f2bf(tile[ir * 33 + jo + e]);
            *(unsigned long long*)(Pb + (size_t)(ic * 64 + ir) * T + j0 + jo) = pk.u;
        }
        __syncthreads();
    }
}

// ---------------------------------------------------------------------------
extern "C" void kernel_launch(void* const* d_in, const int* in_sizes, int n_in,
                              void* d_out, int out_size, void* d_ws, size_t ws_size,
                              hipStream_t stream)
{
    const int B = 4, T = 2048, E = 1024, H = 1024;
    const int M = B * T;                       // 8192
    const float* X  = (const float*)d_in[0];
    const float* Wq = (const float*)d_in[1];
    const float* Wk = (const float*)d_in[2];
    const float* Wv = (const float*)d_in[3];
    float* out = (float*)d_out;
    char* ws = (char*)d_ws;
    const size_t MB = 1024 * 1024;

    unsigned short* Xb  = (unsigned short*)(ws + 0);        // [ 0,16) MB
    unsigned short* WqT = (unsigned short*)(ws + 16 * MB);  // [16,18) contiguous with WkT,WvT
    unsigned short* WkT = (unsigned short*)(ws + 18 * MB);  // [18,20)
    unsigned short* WvT = (unsigned short*)(ws + 20 * MB);  // [20,22)
    unsigned short* Qb  = (unsigned short*)(ws + 32 * MB);  // [32,48)
    unsigned short* Kb  = (unsigned short*)(ws + 48 * MB);  // [48,64)
    unsigned short* Vt  = (unsigned short*)(ws + 64 * MB);  // [64,80) Vt [B,H,T]
    unsigned short* St  = (unsigned short*)(ws + 0);        // [ 0,32) overlays Xb/W (dead)
    unsigned short* P   = (unsigned short*)(ws + 32 * MB);  // [32,64) overlays Qb/Kb (dead)

    // 1. casts / weight transposes
    cast_kernel<<<dim3((M * E) / 1024), 256, 0, stream>>>(X, Xb, (size_t)M * E);
    transpose_cast_kernel<<<dim3(H / 64, E / 64), 256, 0, stream>>>(Wq, WqT, E, H);
    transpose_cast_kernel<<<dim3(H / 64, E / 64), 256, 0, stream>>>(Wk, WkT, E, H);
    transpose_cast_kernel<<<dim3(H / 64, E / 64), 256, 0, stream>>>(Wv, WvT, E, H);

    // 2. fused QKV: [8192,3072] vs concat W^T; Q,K row-major, V -> Vt [B,H,T]
    gemm_nt<4><<<dim3(3 * H / 128, M / 128, 1), 256, 0, stream>>>(
        Xb, WqT, Qb, Kb, Vt, M, 3 * H, E, 0, 0, 0, 1.f, T);

    // 3. scores, written TRANSPOSED: St[j][i] = (Q K^T)[i][j] / 32
    gemm_nt<1><<<dim3(T / 128, T / 128, B), 256, 0, stream>>>(
        Qb, Kb, St, nullptr, nullptr, T, T, H,
        (size_t)T * H, (size_t)T * H, (size_t)T * T, 0.03125f, T);

    // 4. softmax over i per column j (row-contiguous on St), P[i][j] bf16
    col_softmax_t<<<dim3(T / 32, B), 256, 0, stream>>>(St, P, T);

    // 5. out = P V  (NT with V^T), causal K-limit
    gemm_nt<2><<<dim3(H / 128, T / 128, B), 256, 0, stream>>>(
        P, Vt, out, nullptr, nullptr, T, H, T,
        (size_t)T * T, (size_t)H * T, (size_t)T * H, 1.f, 0);
}

// Round 7
// 287.798 us; speedup vs baseline: 1.6753x; 1.0087x over previous
//
#include <hip/hip_runtime.h>
#include <hip/hip_bf16.h>
#include <stdint.h>

// ---------------------------------------------------------------------------
// MaskedAttention: out = colsoftmax(tril(Q K^T / sqrt(E))) @ V
// B=4, T=2048, E=H=1024.  Softmax over the QUERY axis (axis=1) per column j.
//
// R6/R7 change (R5 profile: QKV GEMM 71us, MfmaUtil 30%, SQ_LDS_BANK_CONFLICT
// 6.29M = ~15% of cycles; ds_read_b128 rows at 64B stride -> 8-way conflict):
//  * XOR-swizzled LDS layout: chunk (row,g) stored at slot g^((row>>1)&3).
//    Read side is lane-constant (lk = ((lane>>4)^((lane>>1)&3))*8, since row
//    bits 1..2 == lrow bits 1..2) -> zero extra VALU; lanes cover all 32
//    banks 2-way (free, m136).  Staging fetches the permuted global chunk.
//  (R6 failed to compile: extra '(' on the lk line.)
//
// Workspace 80 MB, liveness overlays:
//   [ 0,16) Xb      (dead after QKV)      -> St bf16 [0,32) at scores step
//   [16,22) WqT|WkT|WvT contiguous [3072,1024] (dead after QKV)
//   [32,48) Qb      (dead after scores)   -> P bf16 [32,64) at softmax step
//   [48,64) Kb      (dead after scores)
//   [64,80) Vt [B,H,T] (alive to PV, written by fused-GEMM V epilogue)
// ---------------------------------------------------------------------------

typedef short bf16x8 __attribute__((ext_vector_type(8)));
typedef float f32x4  __attribute__((ext_vector_type(4)));

__device__ __forceinline__ unsigned short f2bf(float f) {
    union { float f; unsigned u; } x; x.f = f;
    unsigned r = x.u + 0x7FFFu + ((x.u >> 16) & 1u);
    return (unsigned short)(r >> 16);
}
__device__ __forceinline__ float bf2f(unsigned short h) {
    union { unsigned u; float f; } x; x.u = ((unsigned)h) << 16;
    return x.f;
}

// 16B-per-lane async global->LDS copy. dst must be wave-uniform; HW adds lane*16.
__device__ __forceinline__ void async16(void* lds, const void* g) {
    __builtin_amdgcn_global_load_lds(
        (__attribute__((address_space(1))) void*)(void*)g,
        (__attribute__((address_space(3))) void*)lds,
        16, 0, 0);
}

// ---------------------------------------------------------------------------
__global__ __launch_bounds__(256) void cast_kernel(
    const float* __restrict__ in, unsigned short* __restrict__ out, size_t n)
{
    size_t i = ((size_t)blockIdx.x * 256 + threadIdx.x) * 4;
    if (i >= n) return;
    float4 v = *(const float4*)(in + i);
    union { unsigned short h[4]; unsigned long long u; } p;
    p.h[0] = f2bf(v.x); p.h[1] = f2bf(v.y); p.h[2] = f2bf(v.z); p.h[3] = f2bf(v.w);
    *(unsigned long long*)(out + i) = p.u;
}

// transpose + cast: W [R,C] fp32 -> Wt [C,R] bf16. 64x64 tile, 256 threads.
__global__ __launch_bounds__(256) void transpose_cast_kernel(
    const float* __restrict__ in, unsigned short* __restrict__ out, int R, int C)
{
    __shared__ unsigned short tile[64][65];
    int tx = threadIdx.x & 63, ty = threadIdx.x >> 6;
    int r0 = blockIdx.y * 64, c0 = blockIdx.x * 64;
#pragma unroll
    for (int i = 0; i < 16; ++i) {
        int r = ty + i * 4;
        tile[r][tx] = f2bf(in[(size_t)(r0 + r) * C + c0 + tx]);
    }
    __syncthreads();
#pragma unroll
    for (int i = 0; i < 16; ++i) {
        int c = ty + i * 4;
        out[(size_t)(c0 + c) * R + r0 + tx] = tile[tx][c];
    }
}

// ---------------------------------------------------------------------------
// NT bf16 GEMM: C[M,N] = A[M,K] * B[N,K]^T
// 128x128 tile, BK=64 (two BK=32 halves), 256 threads = 4 waves of 64x64,
// 16x16x32 bf16 MFMA, width-16 global_load_lds staging, XOR-swizzled LDS.
// MODE 1: C bf16 TRANSPOSED * scale, tm<tn skip  (scores -> St[j][i]), ldt=T
// MODE 2: C fp32, K limited to m0+128            (PV; P causally zero-filled)
// MODE 4: fused QKV epilogue: n0<1024 -> Cout (Q rowmajor), <2048 -> C2 (K
//         rowmajor), else C3 (V transposed [B,H,T], batch from m0), ldt=T
// ---------------------------------------------------------------------------
template <int MODE>
__global__ __launch_bounds__(256) void gemm_nt(
    const unsigned short* __restrict__ A, const unsigned short* __restrict__ B,
    void* __restrict__ Cout, unsigned short* __restrict__ C2,
    unsigned short* __restrict__ C3, int M, int N, int K,
    size_t sAb, size_t sBb, size_t sCb, float scale, int ldt)
{
    int tn = blockIdx.x, tm = blockIdx.y, bz = blockIdx.z;
    if (MODE == 1 && tm < tn) return;   // strictly-upper tile: never read later
    A += (size_t)bz * sAb;
    B += (size_t)bz * sBb;
    int m0 = tm * 128, n0 = tn * 128;
    int kmax = (MODE == 2) ? (m0 + 128) : K;

    __shared__ unsigned short sA[128 * 64];   // two 128x32 halves, consecutive
    __shared__ unsigned short sB[128 * 64];

    unsigned t = threadIdx.x, lane = t & 63, wave = t >> 6;

    // staging: 1024 16B-chunks per tile; chunk ca: half = ca>>9,
    // row = (ca&511)>>2, LDS slot = ca&3.  Swizzle: the global 16B group
    // g = slot ^ ((row>>1)&3) lands in this slot (bank-spread on read).
    const unsigned short* gA[4]; const unsigned short* gB[4];
    char* lA[4]; char* lB[4];
#pragma unroll
    for (int q = 0; q < 4; ++q) {
        unsigned ca = t + 256u * q;
        unsigned row = (ca & 511) >> 2;
        unsigned g = (ca & 3) ^ ((row >> 1) & 3);
        unsigned col = (ca >> 9) * 32 + g * 8;
        gA[q] = A + (size_t)(m0 + row) * K + col;
        gB[q] = B + (size_t)(n0 + row) * K + col;
        lA[q] = (char*)sA + (size_t)(t - lane + 256u * q) * 16;
        lB[q] = (char*)sB + (size_t)(t - lane + 256u * q) * 16;
    }

    unsigned wm = (wave >> 1) * 64, wn = (wave & 1) * 64;
    unsigned lrow = lane & 15;
    // swizzled k-offset: row bits 1..2 == lrow bits 1..2 (wm+i*16 mult of 16),
    // so the slot is lane-constant: ((lane>>4) ^ ((lane>>1)&3)) * 8 shorts.
    unsigned lk = ((lane >> 4) ^ ((lane >> 1) & 3)) * 8;
    const short* sAs = (const short*)sA;
    const short* sBs = (const short*)sB;

    f32x4 acc[4][4] = {};

    for (int k0 = 0; k0 < kmax; k0 += 64) {
        __syncthreads();                 // prior iter's LDS reads complete
#pragma unroll
        for (int q = 0; q < 4; ++q) {
            async16(lA[q], gA[q]); async16(lB[q], gB[q]);
            gA[q] += 64; gB[q] += 64;
        }
        __syncthreads();                 // vmcnt(0) drain before barrier

#pragma unroll
        for (int kk = 0; kk < 2; ++kk) {
            bf16x8 a[4], b[4];
#pragma unroll
            for (int i = 0; i < 4; ++i) {
                a[i] = *(const bf16x8*)(sAs + kk * 4096 + (wm + i * 16 + lrow) * 32 + lk);
                b[i] = *(const bf16x8*)(sBs + kk * 4096 + (wn + i * 16 + lrow) * 32 + lk);
            }
#pragma unroll
            for (int i = 0; i < 4; ++i)
#pragma unroll
                for (int j = 0; j < 4; ++j)
                    acc[i][j] = __builtin_amdgcn_mfma_f32_16x16x32_bf16(
                        a[i], b[j], acc[i][j], 0, 0, 0);
        }
    }

    // epilogue: D col = lane&15, row = (lane>>4)*4 + reg
    unsigned col = lane & 15, rq = (lane >> 4) * 4;
    if (MODE == 1) {          // transposed + scale: St[j][i], 4 bf16 packed
        unsigned short* C = (unsigned short*)Cout + (size_t)bz * sCb;
#pragma unroll
        for (int i = 0; i < 4; ++i)
#pragma unroll
            for (int j = 0; j < 4; ++j) {
                union { unsigned short h[4]; unsigned long long u; } p;
#pragma unroll
                for (int r = 0; r < 4; ++r) p.h[r] = f2bf(acc[i][j][r] * scale);
                int jg = n0 + wn + j * 16 + col;
                int ig = m0 + wm + i * 16 + rq;
                *(unsigned long long*)(C + (size_t)jg * ldt + ig) = p.u;
            }
    } else if (MODE == 2) {
        float* C = (float*)Cout + (size_t)bz * sCb;
#pragma unroll
        for (int i = 0; i < 4; ++i)
#pragma unroll
            for (int j = 0; j < 4; ++j)
#pragma unroll
                for (int r = 0; r < 4; ++r)
                    C[(size_t)(m0 + wm + i * 16 + rq + r) * N + n0 + wn + j * 16 + col] =
                        acc[i][j][r];
    } else {                  // MODE 4: fused QKV
        if (n0 < 2048) {      // Q or K, row-major [8192,1024]
            unsigned short* C = (n0 < 1024) ? (unsigned short*)Cout : C2;
            int nb = n0 & 1023;
#pragma unroll
            for (int i = 0; i < 4; ++i)
#pragma unroll
                for (int j = 0; j < 4; ++j)
#pragma unroll
                    for (int r = 0; r < 4; ++r)
                        C[(size_t)(m0 + wm + i * 16 + rq + r) * 1024 + nb + wn + j * 16 + col] =
                            f2bf(acc[i][j][r]);
        } else {              // V transposed into Vt [B,H,T]
            int batch = m0 >> 11, tb = m0 & 2047;
            unsigned short* C = C3 + (size_t)batch * 1024 * 2048;
#pragma unroll
            for (int i = 0; i < 4; ++i)
#pragma unroll
                for (int j = 0; j < 4; ++j) {
                    union { unsigned short h[4]; unsigned long long u; } p;
#pragma unroll
                    for (int r = 0; r < 4; ++r) p.h[r] = f2bf(acc[i][j][r]);
                    int h = (n0 - 2048) + wn + j * 16 + col;
                    int t0 = tb + wm + i * 16 + rq;
                    *(unsigned long long*)(C + (size_t)h * ldt + t0) = p.u;
                }
        }
    }
}

// ---------------------------------------------------------------------------
// Softmax over query axis i (per column j), on TRANSPOSED scores St[j][i].
// Block = 32 columns, 256 threads. Phase 1: per-column online (m,l) with
// bf16x8 coalesced loads + shfl butterfly. Phase 2: p + LDS transpose +
// coalesced P[i][j] writes (zeros above diagonal for PV's diagonal tiles).
// ---------------------------------------------------------------------------
__global__ __launch_bounds__(256) void col_softmax_t(
    const unsigned short* __restrict__ St, unsigned short* __restrict__ P, int T)
{
    const int b = blockIdx.y;
    const int j0 = blockIdx.x * 32;
    const unsigned short* Sb = St + (size_t)b * T * T;
    unsigned short* Pb = P + (size_t)b * T * T;
    const int t = threadIdx.x, lane = t & 63, wave = t >> 6;

    __shared__ float fm[32], fl[32];
    __shared__ float tile[64 * 33];

    // ---- phase 1: per-column max & sum ----
    for (int jj = 0; jj < 8; ++jj) {
        const int jl = wave * 8 + jj, j = j0 + jl;
        const unsigned short* row = Sb + (size_t)j * T;
        float m = -1e30f, l = 0.f;
        for (int it = j >> 9; it < (T >> 9); ++it) {
            const int i0 = it * 512 + lane * 8;
            bf16x8 v = *(const bf16x8*)(row + i0);
            float s[8];
#pragma unroll
            for (int e = 0; e < 8; ++e)
                s[e] = (i0 + e >= j) ? bf2f((unsigned short)v[e]) : -1e30f;
            float m8 = s[0];
#pragma unroll
            for (int e = 1; e < 8; ++e) m8 = fmaxf(m8, s[e]);
            const float mn = fmaxf(m, m8);
            float a = 0.f;
#pragma unroll
            for (int e = 0; e < 8; ++e) a += __expf(s[e] - mn);
            l = l * __expf(m - mn) + a;
            m = mn;
        }
#pragma unroll
        for (int d = 1; d < 64; d <<= 1) {
            const float mo = __shfl_xor(m, d);
            const float lo = __shfl_xor(l, d);
            const float mn = fmaxf(m, mo);
            l = l * __expf(m - mn) + lo * __expf(mo - mn);
            m = mn;
        }
        if (lane == 0) { fm[jl] = m; fl[jl] = 1.0f / l; }
    }
    __syncthreads();

    // ---- phase 2: probabilities + LDS transpose + coalesced P write ----
    const int jl = t >> 3;               // 0..31
    const int j = j0 + jl;
    const int is = (t & 7) * 8;          // 0..56
    const float M = fm[jl], Li = fl[jl];
    const int il = t >> 3, jo = (t & 7) * 4;

    for (int ic = (j0 >> 7) << 1; ic < (T >> 6); ++ic) {
        bf16x8 v = *(const bf16x8*)(Sb + (size_t)j * T + ic * 64 + is);
#pragma unroll
        for (int k = 0; k < 8; ++k) {
            const int i = ic * 64 + is + k;
            const float s = bf2f((unsigned short)v[k]);
            tile[(is + k) * 33 + jl] = (i >= j) ? __expf(s - M) * Li : 0.f;
        }
        __syncthreads();
#pragma unroll
        for (int r = 0; r < 2; ++r) {
            const int ir = il + r * 32;
            union { unsigned short h[4]; unsigned long long u; } pk;
#pragma unroll
            for (int e = 0; e < 4; ++e) pk.h[e] = f2bf(tile[ir * 33 + jo + e]);
            *(unsigned long long*)(Pb + (size_t)(ic * 64 + ir) * T + j0 + jo) = pk.u;
        }
        __syncthreads();
    }
}

// ---------------------------------------------------------------------------
extern "C" void kernel_launch(void* const* d_in, const int* in_sizes, int n_in,
                              void* d_out, int out_size, void* d_ws, size_t ws_size,
                              hipStream_t stream)
{
    const int B = 4, T = 2048, E = 1024, H = 1024;
    const int M = B * T;                       // 8192
    const float* X  = (const float*)d_in[0];
    const float* Wq = (const float*)d_in[1];
    const float* Wk = (const float*)d_in[2];
    const float* Wv = (const float*)d_in[3];
    float* out = (float*)d_out;
    char* ws = (char*)d_ws;
    const size_t MB = 1024 * 1024;

    unsigned short* Xb  = (unsigned short*)(ws + 0);        // [ 0,16) MB
    unsigned short* WqT = (unsigned short*)(ws + 16 * MB);  // [16,18) contiguous with WkT,WvT
    unsigned short* WkT = (unsigned short*)(ws + 18 * MB);  // [18,20)
    unsigned short* WvT = (unsigned short*)(ws + 20 * MB);  // [20,22)
    unsigned short* Qb  = (unsigned short*)(ws + 32 * MB);  // [32,48)
    unsigned short* Kb  = (unsigned short*)(ws + 48 * MB);  // [48,64)
    unsigned short* Vt  = (unsigned short*)(ws + 64 * MB);  // [64,80) Vt [B,H,T]
    unsigned short* St  = (unsigned short*)(ws + 0);        // [ 0,32) overlays Xb/W (dead)
    unsigned short* P   = (unsigned short*)(ws + 32 * MB);  // [32,64) overlays Qb/Kb (dead)

    // 1. casts / weight transposes
    cast_kernel<<<dim3((M * E) / 1024), 256, 0, stream>>>(X, Xb, (size_t)M * E);
    transpose_cast_kernel<<<dim3(H / 64, E / 64), 256, 0, stream>>>(Wq, WqT, E, H);
    transpose_cast_kernel<<<dim3(H / 64, E / 64), 256, 0, stream>>>(Wk, WkT, E, H);
    transpose_cast_kernel<<<dim3(H / 64, E / 64), 256, 0, stream>>>(Wv, WvT, E, H);

    // 2. fused QKV: [8192,3072] vs concat W^T; Q,K row-major, V -> Vt [B,H,T]
    gemm_nt<4><<<dim3(3 * H / 128, M / 128, 1), 256, 0, stream>>>(
        Xb, WqT, Qb, Kb, Vt, M, 3 * H, E, 0, 0, 0, 1.f, T);

    // 3. scores, written TRANSPOSED: St[j][i] = (Q K^T)[i][j] / 32
    gemm_nt<1><<<dim3(T / 128, T / 128, B), 256, 0, stream>>>(
        Qb, Kb, St, nullptr, nullptr, T, T, H,
        (size_t)T * H, (size_t)T * H, (size_t)T * T, 0.03125f, T);

    // 4. softmax over i per column j (row-contiguous on St), P[i][j] bf16
    col_softmax_t<<<dim3(T / 32, B), 256, 0, stream>>>(St, P, T);

    // 5. out = P V  (NT with V^T), causal K-limit
    gemm_nt<2><<<dim3(H / 128, T / 128, B), 256, 0, stream>>>(
        P, Vt, out, nullptr, nullptr, T, H, T,
        (size_t)T * T, (size_t)H * T, (size_t)T * H, 1.f, 0);
}